// Round 1
// baseline (492.507 us; speedup 1.0000x reference)
//
#include <hip/hip_runtime.h>
#include <hip/hip_bf16.h>

#define NN 50000
#define NE 800000
#define EPS 1e-5f

// ---------------- CSR build ----------------

__global__ void k_zero(int* __restrict__ p, int n) {
    int i = blockIdx.x * blockDim.x + threadIdx.x;
    for (; i < n; i += gridDim.x * blockDim.x) p[i] = 0;
}

__global__ void k_hist(const int* __restrict__ tgt, int* __restrict__ deg, int E) {
    int i = blockIdx.x * blockDim.x + threadIdx.x;
    for (; i < E; i += gridDim.x * blockDim.x) atomicAdd(&deg[tgt[i]], 1);
}

// single-block exclusive scan over n elements -> rowstart[0..n], cursor copy
__global__ __launch_bounds__(1024) void k_scan(const int* __restrict__ deg,
                                               int* __restrict__ rowstart,
                                               int* __restrict__ cursor, int n) {
    __shared__ int buf[1024];
    __shared__ int carry_s;
    int tid = threadIdx.x;
    if (tid == 0) carry_s = 0;
    __syncthreads();
    for (int base = 0; base < n; base += 1024) {
        int i = base + tid;
        int v = (i < n) ? deg[i] : 0;
        buf[tid] = v;
        __syncthreads();
        for (int off = 1; off < 1024; off <<= 1) {
            int t = (tid >= off) ? buf[tid - off] : 0;
            __syncthreads();
            buf[tid] += t;
            __syncthreads();
        }
        int excl = buf[tid] - v;
        int c = carry_s;
        if (i < n) { rowstart[i] = c + excl; cursor[i] = c + excl; }
        __syncthreads();
        if (tid == 0) carry_s = c + buf[1023];
        __syncthreads();
    }
    if (tid == 0) rowstart[n] = carry_s;
}

__global__ void k_fill(const int* __restrict__ src, const int* __restrict__ tgt,
                       int* __restrict__ cursor, int* __restrict__ col, int E) {
    int i = blockIdx.x * blockDim.x + threadIdx.x;
    for (; i < E; i += gridDim.x * blockDim.x) {
        int pos = atomicAdd(&cursor[tgt[i]], 1);
        col[pos] = src[i];
    }
}

// ---------------- dense stages ----------------

// h1 = relu(x @ W_in + b_in)   [N,84] @ [84,128]
__global__ __launch_bounds__(128) void k_in(const float* __restrict__ x,
                                            const float* __restrict__ W,
                                            const float* __restrict__ b,
                                            float* __restrict__ h1, int N) {
    __shared__ float xs[8 * 84];
    int r0 = blockIdx.x * 8;
    int tid = threadIdx.x;
    for (int i = tid; i < 8 * 84; i += 128) xs[i] = x[r0 * 84 + i];
    __syncthreads();
    float acc[8];
#pragma unroll
    for (int r = 0; r < 8; r++) acc[r] = 0.f;
    for (int k = 0; k < 84; k++) {
        float w = W[k * 128 + tid];
#pragma unroll
        for (int r = 0; r < 8; r++) acc[r] += xs[r * 84 + k] * w;
    }
    float bb = b[tid];
#pragma unroll
    for (int r = 0; r < 8; r++) {
        float v = acc[r] + bb;
        h1[(r0 + r) * 128 + tid] = v > 0.f ? v : 0.f;
    }
}

// p1 = h1 @ Wl1 ; r1 = h1 @ Wr1 + bl1    (128 -> 64), 4 nodes/block
__global__ __launch_bounds__(256) void k_proj1(const float* __restrict__ h1,
                                               const float* __restrict__ Wl,
                                               const float* __restrict__ Wr,
                                               const float* __restrict__ bl,
                                               float* __restrict__ p1,
                                               float* __restrict__ r1, int N) {
    __shared__ float hs[4][128];
    int node0 = blockIdx.x * 4;
    int tid = threadIdx.x;
    for (int i = tid; i < 4 * 128; i += 256) hs[i >> 7][i & 127] = h1[node0 * 128 + i];
    __syncthreads();
    int c = tid & 63, w = tid >> 6;
    float ap = 0.f, ar = 0.f;
    for (int k = 0; k < 128; k++) {
        float h = hs[w][k];
        ap += h * Wl[k * 64 + c];
        ar += h * Wr[k * 64 + c];
    }
    p1[(node0 + w) * 64 + c] = ap;
    r1[(node0 + w) * 64 + c] = ar + bl[c];
}

// agg over CSR + layernorm + relu, C=64: one 64-lane wave per node
__global__ __launch_bounds__(256) void k_agg_ln64(const float* __restrict__ p,
                                                  const float* __restrict__ r,
                                                  const int* __restrict__ rowstart,
                                                  const int* __restrict__ col,
                                                  const float* __restrict__ g,
                                                  const float* __restrict__ be,
                                                  float* __restrict__ out, int N) {
    int tid = threadIdx.x;
    int c = tid & 63;
    int n = blockIdx.x * 4 + (tid >> 6);
    if (n >= N) return;
    int s0 = rowstart[n], s1 = rowstart[n + 1];
    float s = 0.f;
    for (int i = s0; i < s1; i++) s += p[col[i] * 64 + c];
    int cnt = s1 - s0;
    float v = s / (float)(cnt > 1 ? cnt : 1) + r[n * 64 + c];
    float m = v;
#pragma unroll
    for (int o = 1; o < 64; o <<= 1) m += __shfl_xor(m, o, 64);
    m *= (1.f / 64.f);
    float d = v - m;
    float var = d * d;
#pragma unroll
    for (int o = 1; o < 64; o <<= 1) var += __shfl_xor(var, o, 64);
    var *= (1.f / 64.f);
    float y = d * rsqrtf(var + EPS) * g[c] + be[c];
    out[n * 64 + c] = y > 0.f ? y : 0.f;
}

// p2 = h2 @ Wl2 ; r2 = h2 @ Wr2 + bl2   (64 -> 32), 8 nodes/block
__global__ __launch_bounds__(256) void k_proj2(const float* __restrict__ h2,
                                               const float* __restrict__ Wl,
                                               const float* __restrict__ Wr,
                                               const float* __restrict__ bl,
                                               float* __restrict__ p2,
                                               float* __restrict__ r2, int N) {
    __shared__ float hs[8][64];
    int node0 = blockIdx.x * 8;
    int tid = threadIdx.x;
    for (int i = tid; i < 8 * 64; i += 256) hs[i >> 6][i & 63] = h2[node0 * 64 + i];
    __syncthreads();
    int c = tid & 31, w = tid >> 5;
    float ap = 0.f, ar = 0.f;
    for (int k = 0; k < 64; k++) {
        float h = hs[w][k];
        ap += h * Wl[k * 32 + c];
        ar += h * Wr[k * 32 + c];
    }
    p2[(node0 + w) * 32 + c] = ap;
    r2[(node0 + w) * 32 + c] = ar + bl[c];
}

// agg + LN + relu, C=32: 32 lanes per node, 8 nodes/block
__global__ __launch_bounds__(256) void k_agg_ln32(const float* __restrict__ p,
                                                  const float* __restrict__ r,
                                                  const int* __restrict__ rowstart,
                                                  const int* __restrict__ col,
                                                  const float* __restrict__ g,
                                                  const float* __restrict__ be,
                                                  float* __restrict__ out, int N) {
    int tid = threadIdx.x;
    int c = tid & 31;
    int n = blockIdx.x * 8 + (tid >> 5);
    if (n >= N) return;
    int s0 = rowstart[n], s1 = rowstart[n + 1];
    float s = 0.f;
    for (int i = s0; i < s1; i++) s += p[col[i] * 32 + c];
    int cnt = s1 - s0;
    float v = s / (float)(cnt > 1 ? cnt : 1) + r[n * 32 + c];
    float m = v;
#pragma unroll
    for (int o = 1; o < 32; o <<= 1) m += __shfl_xor(m, o, 32);
    m *= (1.f / 32.f);
    float d = v - m;
    float var = d * d;
#pragma unroll
    for (int o = 1; o < 32; o <<= 1) var += __shfl_xor(var, o, 32);
    var *= (1.f / 32.f);
    float y = d * rsqrtf(var + EPS) * g[c] + be[c];
    out[n * 32 + c] = y > 0.f ? y : 0.f;
}

// out = relu(h3 @ Wo1 + bo1) @ Wo2 + bo2 : 16 lanes/node, 16 nodes/block
__global__ __launch_bounds__(256) void k_out(const float* __restrict__ h3,
                                             const float* __restrict__ Wo1,
                                             const float* __restrict__ bo1,
                                             const float* __restrict__ Wo2,
                                             const float* __restrict__ bo2,
                                             float* __restrict__ out, int N) {
    __shared__ float hs[16][32];
    int node0 = blockIdx.x * 16;
    int tid = threadIdx.x;
    for (int i = tid; i < 16 * 32; i += 256) hs[i >> 5][i & 31] = h3[node0 * 32 + i];
    __syncthreads();
    int j = tid & 15, w = tid >> 4;
    float a = bo1[j];
#pragma unroll
    for (int k = 0; k < 32; k++) a += hs[w][k] * Wo1[k * 16 + j];
    a = a > 0.f ? a : 0.f;
    float contrib = a * Wo2[j];
#pragma unroll
    for (int o = 1; o < 16; o <<= 1) contrib += __shfl_xor(contrib, o, 16);
    if (j == 0) out[node0 + w] = contrib + bo2[0];
}

extern "C" void kernel_launch(void* const* d_in, const int* in_sizes, int n_in,
                              void* d_out, int out_size, void* d_ws, size_t ws_size,
                              hipStream_t stream) {
    const float* x    = (const float*)d_in[0];
    const int*   ei   = (const int*)d_in[1];
    const float* W_in = (const float*)d_in[2];
    const float* b_in = (const float*)d_in[3];
    const float* Wl1  = (const float*)d_in[4];
    const float* bl1  = (const float*)d_in[5];
    const float* Wr1  = (const float*)d_in[6];
    const float* g1   = (const float*)d_in[7];
    const float* be1  = (const float*)d_in[8];
    const float* Wl2  = (const float*)d_in[9];
    const float* bl2  = (const float*)d_in[10];
    const float* Wr2  = (const float*)d_in[11];
    const float* g2   = (const float*)d_in[12];
    const float* be2  = (const float*)d_in[13];
    const float* Wo1  = (const float*)d_in[14];
    const float* bo1  = (const float*)d_in[15];
    const float* Wo2  = (const float*)d_in[16];
    const float* bo2  = (const float*)d_in[17];
    float* out = (float*)d_out;

    const int N = NN, E = NE;
    const int* src = ei;
    const int* tgt = ei + E;

    // workspace layout (with buffer reuse)
    char* w = (char*)d_ws;
    int* deg      = (int*)w;                 w += (size_t)N * 4;
    int* rowstart = (int*)w;                 w += (size_t)(N + 1) * 4;
    int* cursor   = (int*)w;                 w += (size_t)N * 4;
    int* col      = (int*)w;                 w += (size_t)E * 4;
    // align to 16B
    w = (char*)(((uintptr_t)w + 15) & ~(uintptr_t)15);
    float* h1 = (float*)w;                   // N*128 floats; reused region
    float* h2 = h1;                          // N*64  (h1 dead after proj1)
    float* p2 = h1 + (size_t)N * 64;         // N*32  (upper half of h1 region)
    float* r2 = p2 + (size_t)N * 32;         // N*32
    w += (size_t)N * 128 * 4;
    float* p1 = (float*)w;                   // N*64
    float* h3 = p1;                          // N*32 (p1 dead after proj2)
    w += (size_t)N * 64 * 4;
    float* r1 = (float*)w;                   // N*64

    // ---- CSR build (shared by both layers) ----
    k_zero<<<256, 256, 0, stream>>>(deg, N);
    k_hist<<<1024, 256, 0, stream>>>(tgt, deg, E);
    k_scan<<<1, 1024, 0, stream>>>(deg, rowstart, cursor, N);
    k_fill<<<1024, 256, 0, stream>>>(src, tgt, cursor, col, E);

    // ---- dense pipeline ----
    k_in<<<N / 8, 128, 0, stream>>>(x, W_in, b_in, h1, N);
    k_proj1<<<N / 4, 256, 0, stream>>>(h1, Wl1, Wr1, bl1, p1, r1, N);
    k_agg_ln64<<<N / 4, 256, 0, stream>>>(p1, r1, rowstart, col, g1, be1, h2, N);
    k_proj2<<<N / 8, 256, 0, stream>>>(h2, Wl2, Wr2, bl2, p2, r2, N);
    k_agg_ln32<<<N / 8, 256, 0, stream>>>(p2, r2, rowstart, col, g2, be2, h3, N);
    k_out<<<N / 16, 256, 0, stream>>>(h3, Wo1, bo1, Wo2, bo2, out, N);
}

// Round 2
// 283.641 us; speedup vs baseline: 1.7364x; 1.7364x over previous
//
#include <hip/hip_runtime.h>
#include <hip/hip_bf16.h>

#define NN 50000
#define NE 800000
#define EPS 1e-5f

// ---------------- CSR build ----------------

__global__ void k_zero(int* __restrict__ p, int n) {
    int i = blockIdx.x * blockDim.x + threadIdx.x;
    for (; i < n; i += gridDim.x * blockDim.x) p[i] = 0;
}

__global__ void k_hist(const int* __restrict__ tgt, int* __restrict__ deg, int E) {
    int i = blockIdx.x * blockDim.x + threadIdx.x;
    for (; i < E; i += gridDim.x * blockDim.x) atomicAdd(&deg[tgt[i]], 1);
}

__device__ __forceinline__ int waveInclScan(int v, int lane) {
#pragma unroll
    for (int o = 1; o < 64; o <<= 1) {
        int t = __shfl_up(v, o, 64);
        if (lane >= o) v += t;
    }
    return v;
}

// per-block local exclusive scan + block totals
__global__ __launch_bounds__(256) void k_scanA(const int* __restrict__ deg,
                                               int* __restrict__ locscan,
                                               int* __restrict__ bsum, int n) {
    __shared__ int wt[4];
    int tid = threadIdx.x;
    int gid = blockIdx.x * 256 + tid;
    int lane = tid & 63, w = tid >> 6;
    int v = (gid < n) ? deg[gid] : 0;
    int incl = waveInclScan(v, lane);
    if (lane == 63) wt[w] = incl;
    __syncthreads();
    int off = 0;
#pragma unroll
    for (int j = 0; j < 3; j++) if (j < w) off += wt[j];
    if (gid < n) locscan[gid] = off + incl - v;
    if (tid == 255) bsum[blockIdx.x] = off + incl;
}

// scan block totals (nb <= 256), write grand total to rowend[0]
__global__ __launch_bounds__(256) void k_scanB(int* __restrict__ bsum, int nb,
                                               int* __restrict__ rowend) {
    __shared__ int wt[4];
    int tid = threadIdx.x;
    int lane = tid & 63, w = tid >> 6;
    int v = (tid < nb) ? bsum[tid] : 0;
    int incl = waveInclScan(v, lane);
    if (lane == 63) wt[w] = incl;
    __syncthreads();
    int off = 0;
#pragma unroll
    for (int j = 0; j < 3; j++) if (j < w) off += wt[j];
    if (tid < nb) bsum[tid] = off + incl - v;
    if (tid == 255) rowend[0] = off + incl;
}

__global__ void k_scanC(const int* __restrict__ locscan, const int* __restrict__ bsum,
                        int* __restrict__ rowstart, int* __restrict__ cursor, int n) {
    int gid = blockIdx.x * blockDim.x + threadIdx.x;
    if (gid < n) {
        int v = locscan[gid] + bsum[blockIdx.x];
        rowstart[gid] = v;
        cursor[gid] = v;
    }
}

__global__ void k_fill(const int* __restrict__ src, const int* __restrict__ tgt,
                       int* __restrict__ cursor, int* __restrict__ col, int E) {
    int i = blockIdx.x * blockDim.x + threadIdx.x;
    for (; i < E; i += gridDim.x * blockDim.x) {
        int pos = atomicAdd(&cursor[tgt[i]], 1);
        col[pos] = src[i];
    }
}

// ---------------- fused dense stages ----------------

// x -> p1 = relu(x@W_in+b_in)@Wl1 ; r1 = relu(...)@Wr1 + bl1
// 32 nodes/block, 256 threads. h1 tile lives only in LDS.
__global__ __launch_bounds__(256) void k_in_proj1(const float* __restrict__ x,
                                                  const float* __restrict__ Win,
                                                  const float* __restrict__ bin,
                                                  const float* __restrict__ Wl,
                                                  const float* __restrict__ Wr,
                                                  const float* __restrict__ bl,
                                                  float* __restrict__ p1,
                                                  float* __restrict__ r1, int N) {
    __shared__ float xs[32 * 84];      // 10.5 KB
    __shared__ float hs[32][128];      // 16 KB
    int node0 = blockIdx.x * 32;
    int tid = threadIdx.x;
    for (int i = tid; i < 32 * 84; i += 256) {
        int g = node0 * 84 + i;
        xs[i] = (g < N * 84) ? x[g] : 0.f;
    }
    __syncthreads();

    // phase 1: h1 tile. thread = (c in 0..127, half in 0..1), 16 nodes each
    {
        int c = tid & 127, half = tid >> 7;
        float acc[16];
#pragma unroll
        for (int m = 0; m < 16; m++) acc[m] = 0.f;
        for (int k = 0; k < 84; k++) {
            float w = Win[k * 128 + c];
#pragma unroll
            for (int m = 0; m < 16; m++) acc[m] += xs[(2 * m + half) * 84 + k] * w;
        }
        float bb = bin[c];
#pragma unroll
        for (int m = 0; m < 16; m++) {
            float v = acc[m] + bb;
            hs[2 * m + half][c] = v > 0.f ? v : 0.f;
        }
    }
    __syncthreads();

    // phase 2: projections. thread = (c in 0..63, w in 0..3), 8 nodes each
    {
        int c = tid & 63, w = tid >> 6;
        float ap[8], ar[8];
#pragma unroll
        for (int m = 0; m < 8; m++) { ap[m] = 0.f; ar[m] = 0.f; }
#pragma unroll 2
        for (int k = 0; k < 128; k++) {
            float wl = Wl[k * 64 + c];
            float wr = Wr[k * 64 + c];
#pragma unroll
            for (int m = 0; m < 8; m++) {
                float h = hs[4 * m + w][k];
                ap[m] += h * wl;
                ar[m] += h * wr;
            }
        }
        float bb = bl[c];
#pragma unroll
        for (int m = 0; m < 8; m++) {
            int n = node0 + 4 * m + w;
            if (n < N) {
                p1[n * 64 + c] = ap[m];
                r1[n * 64 + c] = ar[m] + bb;
            }
        }
    }
}

// (p1,r1,CSR) -> p2,r2 : mean-agg + LN + relu (=h2, LDS only) then proj2.
// 4 nodes/block (1 wave each). Wl2/Wr2 staged in LDS.
__global__ __launch_bounds__(256) void k_agg1_proj2(const float* __restrict__ p1,
                                                    const float* __restrict__ r1,
                                                    const int* __restrict__ rowstart,
                                                    const int* __restrict__ col,
                                                    const float* __restrict__ g1,
                                                    const float* __restrict__ be1,
                                                    const float* __restrict__ Wl2,
                                                    const float* __restrict__ Wr2,
                                                    const float* __restrict__ bl2,
                                                    float* __restrict__ p2,
                                                    float* __restrict__ r2, int N) {
    __shared__ float Wlds[2 * 64 * 32];   // 16 KB: [0..2047]=Wl2, [2048..]=Wr2
    __shared__ float ylds[4][64];
    int tid = threadIdx.x;
    for (int i = tid; i < 64 * 32; i += 256) {
        Wlds[i] = Wl2[i];
        Wlds[2048 + i] = Wr2[i];
    }
    int c = tid & 63;
    int wv = tid >> 6;
    int n = blockIdx.x * 4 + wv;
    float y = 0.f;
    if (n < N) {
        int s0 = rowstart[n], s1 = rowstart[n + 1];
        float s = 0.f, s2 = 0.f;
        int i = s0;
        for (; i + 1 < s1; i += 2) {
            s  += p1[col[i] * 64 + c];
            s2 += p1[col[i + 1] * 64 + c];
        }
        if (i < s1) s += p1[col[i] * 64 + c];
        s += s2;
        int cnt = s1 - s0;
        float v = s / (float)(cnt > 1 ? cnt : 1) + r1[n * 64 + c];
        float m = v;
#pragma unroll
        for (int o = 1; o < 64; o <<= 1) m += __shfl_xor(m, o, 64);
        m *= (1.f / 64.f);
        float d = v - m;
        float var = d * d;
#pragma unroll
        for (int o = 1; o < 64; o <<= 1) var += __shfl_xor(var, o, 64);
        var *= (1.f / 64.f);
        float t = d * rsqrtf(var + EPS) * g1[c] + be1[c];
        y = t > 0.f ? t : 0.f;
    }
    ylds[wv][c] = y;
    __syncthreads();
    if (n < N) {
        int cc = c & 31;
        const float* Wb = Wlds + (c >= 32 ? 2048 : 0);
        const float* yr = ylds[wv];
        float a = 0.f;
#pragma unroll 4
        for (int k = 0; k < 64; k++) a += yr[k] * Wb[k * 32 + cc];
        if (c < 32) p2[n * 32 + cc] = a;
        else        r2[n * 32 + cc] = a + bl2[cc];
    }
}

// (p2,r2,CSR) -> out : mean-agg + LN + relu (=h3, LDS only) + 2-layer MLP.
// 8 nodes/block (32 lanes each).
__global__ __launch_bounds__(256) void k_agg2_out(const float* __restrict__ p2,
                                                  const float* __restrict__ r2,
                                                  const int* __restrict__ rowstart,
                                                  const int* __restrict__ col,
                                                  const float* __restrict__ g2,
                                                  const float* __restrict__ be2,
                                                  const float* __restrict__ Wo1,
                                                  const float* __restrict__ bo1,
                                                  const float* __restrict__ Wo2,
                                                  const float* __restrict__ bo2,
                                                  float* __restrict__ out, int N) {
    __shared__ float W1[32 * 16];  // 2 KB
    __shared__ float ylds[8][32];
    __shared__ float b1s[16], w2s[16], b2s;
    int tid = threadIdx.x;
    for (int i = tid; i < 32 * 16; i += 256) W1[i] = Wo1[i];
    if (tid < 16) { b1s[tid] = bo1[tid]; w2s[tid] = Wo2[tid]; }
    if (tid == 0) b2s = bo2[0];
    int c = tid & 31;
    int grp = tid >> 5;
    int n = blockIdx.x * 8 + grp;
    float y = 0.f;
    if (n < N) {
        int s0 = rowstart[n], s1 = rowstart[n + 1];
        float s = 0.f, s2 = 0.f;
        int i = s0;
        for (; i + 1 < s1; i += 2) {
            s  += p2[col[i] * 32 + c];
            s2 += p2[col[i + 1] * 32 + c];
        }
        if (i < s1) s += p2[col[i] * 32 + c];
        s += s2;
        int cnt = s1 - s0;
        float v = s / (float)(cnt > 1 ? cnt : 1) + r2[n * 32 + c];
        float m = v;
#pragma unroll
        for (int o = 1; o < 32; o <<= 1) m += __shfl_xor(m, o, 32);
        m *= (1.f / 32.f);
        float d = v - m;
        float var = d * d;
#pragma unroll
        for (int o = 1; o < 32; o <<= 1) var += __shfl_xor(var, o, 32);
        var *= (1.f / 32.f);
        float t = d * rsqrtf(var + EPS) * g2[c] + be2[c];
        y = t > 0.f ? t : 0.f;
    }
    ylds[grp][c] = y;
    __syncthreads();
    if (n < N && c < 16) {
        const float* yr = ylds[grp];
        float a = b1s[c];
#pragma unroll
        for (int k = 0; k < 32; k++) a += yr[k] * W1[k * 16 + c];
        a = a > 0.f ? a : 0.f;
        float contrib = a * w2s[c];
#pragma unroll
        for (int o = 1; o < 16; o <<= 1) contrib += __shfl_xor(contrib, o, 16);
        if (c == 0) out[n] = contrib + b2s;
    }
}

extern "C" void kernel_launch(void* const* d_in, const int* in_sizes, int n_in,
                              void* d_out, int out_size, void* d_ws, size_t ws_size,
                              hipStream_t stream) {
    const float* x    = (const float*)d_in[0];
    const int*   ei   = (const int*)d_in[1];
    const float* W_in = (const float*)d_in[2];
    const float* b_in = (const float*)d_in[3];
    const float* Wl1  = (const float*)d_in[4];
    const float* bl1  = (const float*)d_in[5];
    const float* Wr1  = (const float*)d_in[6];
    const float* g1   = (const float*)d_in[7];
    const float* be1  = (const float*)d_in[8];
    const float* Wl2  = (const float*)d_in[9];
    const float* bl2  = (const float*)d_in[10];
    const float* Wr2  = (const float*)d_in[11];
    const float* g2   = (const float*)d_in[12];
    const float* be2  = (const float*)d_in[13];
    const float* Wo1  = (const float*)d_in[14];
    const float* bo1  = (const float*)d_in[15];
    const float* Wo2  = (const float*)d_in[16];
    const float* bo2  = (const float*)d_in[17];
    float* out = (float*)d_out;

    const int N = NN, E = NE;
    const int* src = ei;
    const int* tgt = ei + E;
    const int SB = (N + 255) / 256;   // 196

    // workspace layout
    char* w = (char*)d_ws;
    int* deg      = (int*)w;  w += (size_t)N * 4;
    int* locscan  = (int*)w;  w += (size_t)N * 4;
    int* bsum     = (int*)w;  w += 256 * 4;
    int* rowstart = (int*)w;  w += (size_t)(N + 1) * 4;
    int* cursor   = (int*)w;  w += (size_t)N * 4;
    int* col      = (int*)w;  w += (size_t)E * 4;
    w = (char*)(((uintptr_t)w + 15) & ~(uintptr_t)15);
    float* p1 = (float*)w;    w += (size_t)N * 64 * 4;
    float* r1 = (float*)w;    w += (size_t)N * 64 * 4;
    float* p2 = (float*)w;    w += (size_t)N * 32 * 4;
    float* r2 = (float*)w;    w += (size_t)N * 32 * 4;

    // ---- CSR build ----
    k_zero<<<128, 256, 0, stream>>>(deg, N);
    k_hist<<<1024, 256, 0, stream>>>(tgt, deg, E);
    k_scanA<<<SB, 256, 0, stream>>>(deg, locscan, bsum, N);
    k_scanB<<<1, 256, 0, stream>>>(bsum, SB, rowstart + N);
    k_scanC<<<SB, 256, 0, stream>>>(locscan, bsum, rowstart, cursor, N);
    k_fill<<<1024, 256, 0, stream>>>(src, tgt, cursor, col, E);

    // ---- fused pipeline ----
    k_in_proj1<<<(N + 31) / 32, 256, 0, stream>>>(x, W_in, b_in, Wl1, Wr1, bl1, p1, r1, N);
    k_agg1_proj2<<<(N + 3) / 4, 256, 0, stream>>>(p1, r1, rowstart, col, g1, be1,
                                                  Wl2, Wr2, bl2, p2, r2, N);
    k_agg2_out<<<(N + 7) / 8, 256, 0, stream>>>(p2, r2, rowstart, col, g2, be2,
                                                Wo1, bo1, Wo2, bo2, out, N);
}

// Round 3
// 253.894 us; speedup vs baseline: 1.9398x; 1.1172x over previous
//
#include <hip/hip_runtime.h>
#include <hip/hip_bf16.h>
#include <hip/hip_fp16.h>

#define NN 50000
#define NE 800000
#define EPS 1e-5f

// ---------------- CSR build ----------------

__global__ void k_zero(int* __restrict__ p, int n) {
    int i = blockIdx.x * blockDim.x + threadIdx.x;
    for (; i < n; i += gridDim.x * blockDim.x) p[i] = 0;
}

__global__ void k_hist(const int* __restrict__ tgt, int* __restrict__ deg, int E) {
    int i = blockIdx.x * blockDim.x + threadIdx.x;
    for (; i < E; i += gridDim.x * blockDim.x) atomicAdd(&deg[tgt[i]], 1);
}

__device__ __forceinline__ int waveInclScan(int v, int lane) {
#pragma unroll
    for (int o = 1; o < 64; o <<= 1) {
        int t = __shfl_up(v, o, 64);
        if (lane >= o) v += t;
    }
    return v;
}

__global__ __launch_bounds__(256) void k_scanA(const int* __restrict__ deg,
                                               int* __restrict__ locscan,
                                               int* __restrict__ bsum, int n) {
    __shared__ int wt[4];
    int tid = threadIdx.x;
    int gid = blockIdx.x * 256 + tid;
    int lane = tid & 63, w = tid >> 6;
    int v = (gid < n) ? deg[gid] : 0;
    int incl = waveInclScan(v, lane);
    if (lane == 63) wt[w] = incl;
    __syncthreads();
    int off = 0;
#pragma unroll
    for (int j = 0; j < 3; j++) if (j < w) off += wt[j];
    if (gid < n) locscan[gid] = off + incl - v;
    if (tid == 255) bsum[blockIdx.x] = off + incl;
}

__global__ __launch_bounds__(256) void k_scanB(int* __restrict__ bsum, int nb,
                                               int* __restrict__ rowend) {
    __shared__ int wt[4];
    int tid = threadIdx.x;
    int lane = tid & 63, w = tid >> 6;
    int v = (tid < nb) ? bsum[tid] : 0;
    int incl = waveInclScan(v, lane);
    if (lane == 63) wt[w] = incl;
    __syncthreads();
    int off = 0;
#pragma unroll
    for (int j = 0; j < 3; j++) if (j < w) off += wt[j];
    if (tid < nb) bsum[tid] = off + incl - v;
    if (tid == 255) rowend[0] = off + incl;
}

__global__ void k_scanC(const int* __restrict__ locscan, const int* __restrict__ bsum,
                        int* __restrict__ rowstart, int* __restrict__ cursor, int n) {
    int gid = blockIdx.x * blockDim.x + threadIdx.x;
    if (gid < n) {
        int v = locscan[gid] + bsum[blockIdx.x];
        rowstart[gid] = v;
        cursor[gid] = v;
    }
}

__global__ void k_fill(const int* __restrict__ src, const int* __restrict__ tgt,
                       int* __restrict__ cursor, int* __restrict__ col, int E) {
    int i = blockIdx.x * blockDim.x + threadIdx.x;
    for (; i < E; i += gridDim.x * blockDim.x) {
        int pos = atomicAdd(&cursor[tgt[i]], 1);
        col[pos] = src[i];
    }
}

// ---------------- fused dense stages ----------------

// x -> p1 (fp16, packed pairs) = relu(x@Win+bin)@Wl1 ; r1 (fp32) = relu@Wr1 + bl1
// 64 nodes/block, 512 threads.
__global__ __launch_bounds__(512) void k_in_proj1(const float* __restrict__ x,
                                                  const float* __restrict__ Win,
                                                  const float* __restrict__ bin,
                                                  const float* __restrict__ Wl,
                                                  const float* __restrict__ Wr,
                                                  const float* __restrict__ bl,
                                                  __half2* __restrict__ p1v,
                                                  float* __restrict__ r1, int N) {
    __shared__ float xs[64 * 84];      // 21 KB
    __shared__ float hs[64][128];      // 32 KB
    int node0 = blockIdx.x * 64;
    int tid = threadIdx.x;
    for (int i = tid; i < 64 * 84; i += 512) {
        int g = node0 * 84 + i;
        xs[i] = (g < N * 84) ? x[g] : 0.f;
    }
    __syncthreads();

    // phase 1: h tile. thread = (c in 0..127, q in 0..3), 16 nodes each
    {
        int c = tid & 127, q = tid >> 7;
        float acc[16];
#pragma unroll
        for (int m = 0; m < 16; m++) acc[m] = 0.f;
        for (int k = 0; k < 84; k++) {
            float w = Win[k * 128 + c];
#pragma unroll
            for (int m = 0; m < 16; m++) acc[m] += xs[(4 * m + q) * 84 + k] * w;
        }
        float bb = bin[c];
#pragma unroll
        for (int m = 0; m < 16; m++) {
            float v = acc[m] + bb;
            hs[4 * m + q][c] = v > 0.f ? v : 0.f;
        }
    }
    __syncthreads();

    // phase 2: projections. thread = (cc in 0..31 [ch pair], grp in 0..15), 4 nodes each
    {
        int cc = tid & 31, grp = tid >> 5;
        float2 ap[4], ar[4];
#pragma unroll
        for (int j = 0; j < 4; j++) { ap[j] = make_float2(0.f, 0.f); ar[j] = make_float2(0.f, 0.f); }
#pragma unroll 2
        for (int k = 0; k < 128; k++) {
            float2 wl = *reinterpret_cast<const float2*>(&Wl[k * 64 + 2 * cc]);
            float2 wr = *reinterpret_cast<const float2*>(&Wr[k * 64 + 2 * cc]);
#pragma unroll
            for (int j = 0; j < 4; j++) {
                float h = hs[grp + 16 * j][k];
                ap[j].x += h * wl.x; ap[j].y += h * wl.y;
                ar[j].x += h * wr.x; ar[j].y += h * wr.y;
            }
        }
        float2 bb = *reinterpret_cast<const float2*>(&bl[2 * cc]);
#pragma unroll
        for (int j = 0; j < 4; j++) {
            int n = node0 + grp + 16 * j;
            if (n < N) {
                p1v[(size_t)n * 32 + cc] = __floats2half2_rn(ap[j].x, ap[j].y);
                float2 rv = make_float2(ar[j].x + bb.x, ar[j].y + bb.y);
                *reinterpret_cast<float2*>(&r1[(size_t)n * 64 + 2 * cc]) = rv;
            }
        }
    }
}

// (p1 fp16, r1, CSR) -> p2 (fp16), r2 : mean-agg + LN + relu then proj2.
// 8 nodes/block, 32 lanes (=16 half2) per node.
__global__ __launch_bounds__(256) void k_agg1_proj2(const __half2* __restrict__ p1v,
                                                    const float* __restrict__ r1,
                                                    const int* __restrict__ rowstart,
                                                    const int* __restrict__ col,
                                                    const float* __restrict__ g1,
                                                    const float* __restrict__ be1,
                                                    const float* __restrict__ Wl2,
                                                    const float* __restrict__ Wr2,
                                                    const float* __restrict__ bl2,
                                                    __half* __restrict__ p2h,
                                                    float* __restrict__ r2, int N) {
    __shared__ float Wlds[2 * 2048];   // 16 KB: Wl2 | Wr2
    __shared__ float ylds[8][64];      // 2 KB
    int tid = threadIdx.x;
    for (int i = tid; i < 2048; i += 256) {
        Wlds[i] = Wl2[i];
        Wlds[2048 + i] = Wr2[i];
    }
    int cc = tid & 31;
    int grp = tid >> 5;
    int n = blockIdx.x * 8 + grp;
    if (n < N) {
        int s0 = rowstart[n], s1 = rowstart[n + 1];
        float2 a0 = make_float2(0.f, 0.f), a1 = a0, a2 = a0, a3 = a0;
        int i = s0;
        for (; i + 3 < s1; i += 4) {
            float2 v0 = __half22float2(p1v[(size_t)col[i]     * 32 + cc]);
            float2 v1 = __half22float2(p1v[(size_t)col[i + 1] * 32 + cc]);
            float2 v2 = __half22float2(p1v[(size_t)col[i + 2] * 32 + cc]);
            float2 v3 = __half22float2(p1v[(size_t)col[i + 3] * 32 + cc]);
            a0.x += v0.x; a0.y += v0.y;
            a1.x += v1.x; a1.y += v1.y;
            a2.x += v2.x; a2.y += v2.y;
            a3.x += v3.x; a3.y += v3.y;
        }
        for (; i < s1; i++) {
            float2 v0 = __half22float2(p1v[(size_t)col[i] * 32 + cc]);
            a0.x += v0.x; a0.y += v0.y;
        }
        float sx = a0.x + a1.x + a2.x + a3.x;
        float sy = a0.y + a1.y + a2.y + a3.y;
        int cnt = s1 - s0;
        float inv = 1.f / (float)(cnt > 1 ? cnt : 1);
        float2 rr = *reinterpret_cast<const float2*>(&r1[(size_t)n * 64 + 2 * cc]);
        float vx = sx * inv + rr.x;
        float vy = sy * inv + rr.y;
        // LN over 64 channels (2 per lane, 32 lanes)
        float s = vx + vy;
#pragma unroll
        for (int o = 1; o < 32; o <<= 1) s += __shfl_xor(s, o, 32);
        float m = s * (1.f / 64.f);
        float dx = vx - m, dy = vy - m;
        float q = dx * dx + dy * dy;
#pragma unroll
        for (int o = 1; o < 32; o <<= 1) q += __shfl_xor(q, o, 32);
        float rs = rsqrtf(q * (1.f / 64.f) + EPS);
        float y0 = dx * rs * g1[2 * cc] + be1[2 * cc];
        float y1 = dy * rs * g1[2 * cc + 1] + be1[2 * cc + 1];
        ylds[grp][2 * cc]     = y0 > 0.f ? y0 : 0.f;
        ylds[grp][2 * cc + 1] = y1 > 0.f ? y1 : 0.f;
    }
    __syncthreads();
    if (n < N) {
        const float* yr = ylds[grp];
        float ap = 0.f, ar = 0.f;
#pragma unroll 4
        for (int k = 0; k < 64; k++) {
            float y = yr[k];
            ap += y * Wlds[k * 32 + cc];
            ar += y * Wlds[2048 + k * 32 + cc];
        }
        p2h[(size_t)n * 32 + cc] = __float2half_rn(ap);
        r2[(size_t)n * 32 + cc] = ar + bl2[cc];
    }
}

// (p2 fp16, r2, CSR) -> out : mean-agg + LN + relu + 2-layer MLP.
// 16 nodes/block, 16 lanes (=8 half2... 16 half2 lanes of 2ch) per node.
__global__ __launch_bounds__(256) void k_agg2_out(const __half2* __restrict__ p2v,
                                                  const float* __restrict__ r2,
                                                  const int* __restrict__ rowstart,
                                                  const int* __restrict__ col,
                                                  const float* __restrict__ g2,
                                                  const float* __restrict__ be2,
                                                  const float* __restrict__ Wo1,
                                                  const float* __restrict__ bo1,
                                                  const float* __restrict__ Wo2,
                                                  const float* __restrict__ bo2,
                                                  float* __restrict__ out, int N) {
    __shared__ float W1[32 * 16];  // 2 KB
    __shared__ float ylds[16][32];
    __shared__ float b1s[16], w2s[16], b2s;
    int tid = threadIdx.x;
    for (int i = tid; i < 32 * 16; i += 256) W1[i] = Wo1[i];
    if (tid < 16) { b1s[tid] = bo1[tid]; w2s[tid] = Wo2[tid]; }
    if (tid == 0) b2s = bo2[0];
    int l = tid & 15;
    int grp = tid >> 4;
    int n = blockIdx.x * 16 + grp;
    if (n < N) {
        int s0 = rowstart[n], s1 = rowstart[n + 1];
        float2 a0 = make_float2(0.f, 0.f), a1 = a0, a2 = a0, a3 = a0;
        int i = s0;
        for (; i + 3 < s1; i += 4) {
            float2 v0 = __half22float2(p2v[(size_t)col[i]     * 16 + l]);
            float2 v1 = __half22float2(p2v[(size_t)col[i + 1] * 16 + l]);
            float2 v2 = __half22float2(p2v[(size_t)col[i + 2] * 16 + l]);
            float2 v3 = __half22float2(p2v[(size_t)col[i + 3] * 16 + l]);
            a0.x += v0.x; a0.y += v0.y;
            a1.x += v1.x; a1.y += v1.y;
            a2.x += v2.x; a2.y += v2.y;
            a3.x += v3.x; a3.y += v3.y;
        }
        for (; i < s1; i++) {
            float2 v0 = __half22float2(p2v[(size_t)col[i] * 16 + l]);
            a0.x += v0.x; a0.y += v0.y;
        }
        float sx = a0.x + a1.x + a2.x + a3.x;
        float sy = a0.y + a1.y + a2.y + a3.y;
        int cnt = s1 - s0;
        float inv = 1.f / (float)(cnt > 1 ? cnt : 1);
        float2 rr = make_float2(r2[(size_t)n * 32 + 2 * l], r2[(size_t)n * 32 + 2 * l + 1]);
        float vx = sx * inv + rr.x;
        float vy = sy * inv + rr.y;
        float s = vx + vy;
#pragma unroll
        for (int o = 1; o < 16; o <<= 1) s += __shfl_xor(s, o, 16);
        float m = s * (1.f / 32.f);
        float dx = vx - m, dy = vy - m;
        float q = dx * dx + dy * dy;
#pragma unroll
        for (int o = 1; o < 16; o <<= 1) q += __shfl_xor(q, o, 16);
        float rs = rsqrtf(q * (1.f / 32.f) + EPS);
        float y0 = dx * rs * g2[2 * l] + be2[2 * l];
        float y1 = dy * rs * g2[2 * l + 1] + be2[2 * l + 1];
        ylds[grp][2 * l]     = y0 > 0.f ? y0 : 0.f;
        ylds[grp][2 * l + 1] = y1 > 0.f ? y1 : 0.f;
    }
    __syncthreads();
    if (n < N) {
        const float* yr = ylds[grp];
        float a = b1s[l];
#pragma unroll
        for (int k = 0; k < 32; k++) a += yr[k] * W1[k * 16 + l];
        a = a > 0.f ? a : 0.f;
        float contrib = a * w2s[l];
#pragma unroll
        for (int o = 1; o < 16; o <<= 1) contrib += __shfl_xor(contrib, o, 16);
        if (l == 0) out[n] = contrib + b2s;
    }
}

extern "C" void kernel_launch(void* const* d_in, const int* in_sizes, int n_in,
                              void* d_out, int out_size, void* d_ws, size_t ws_size,
                              hipStream_t stream) {
    const float* x    = (const float*)d_in[0];
    const int*   ei   = (const int*)d_in[1];
    const float* W_in = (const float*)d_in[2];
    const float* b_in = (const float*)d_in[3];
    const float* Wl1  = (const float*)d_in[4];
    const float* bl1  = (const float*)d_in[5];
    const float* Wr1  = (const float*)d_in[6];
    const float* g1   = (const float*)d_in[7];
    const float* be1  = (const float*)d_in[8];
    const float* Wl2  = (const float*)d_in[9];
    const float* bl2  = (const float*)d_in[10];
    const float* Wr2  = (const float*)d_in[11];
    const float* g2   = (const float*)d_in[12];
    const float* be2  = (const float*)d_in[13];
    const float* Wo1  = (const float*)d_in[14];
    const float* bo1  = (const float*)d_in[15];
    const float* Wo2  = (const float*)d_in[16];
    const float* bo2  = (const float*)d_in[17];
    float* out = (float*)d_out;

    const int N = NN, E = NE;
    const int* src = ei;
    const int* tgt = ei + E;
    const int SB = (N + 255) / 256;   // 196

    // workspace layout
    char* w = (char*)d_ws;
    int* deg      = (int*)w;  w += (size_t)N * 4;
    int* locscan  = (int*)w;  w += (size_t)N * 4;
    int* bsum     = (int*)w;  w += 256 * 4;
    int* rowstart = (int*)w;  w += (size_t)(N + 1) * 4;
    int* cursor   = (int*)w;  w += (size_t)N * 4;
    int* col      = (int*)w;  w += (size_t)E * 4;
    w = (char*)(((uintptr_t)w + 15) & ~(uintptr_t)15);
    __half2* p1v = (__half2*)w;  w += (size_t)N * 32 * 4;   // N x 64 fp16
    float*   r1  = (float*)w;    w += (size_t)N * 64 * 4;   // N x 64 fp32
    __half*  p2h = (__half*)w;   w += (size_t)N * 32 * 2;   // N x 32 fp16
    w = (char*)(((uintptr_t)w + 15) & ~(uintptr_t)15);
    float*   r2  = (float*)w;    w += (size_t)N * 32 * 4;   // N x 32 fp32

    // ---- CSR build ----
    k_zero<<<128, 256, 0, stream>>>(deg, N);
    k_hist<<<1024, 256, 0, stream>>>(tgt, deg, E);
    k_scanA<<<SB, 256, 0, stream>>>(deg, locscan, bsum, N);
    k_scanB<<<1, 256, 0, stream>>>(bsum, SB, rowstart + N);
    k_scanC<<<SB, 256, 0, stream>>>(locscan, bsum, rowstart, cursor, N);
    k_fill<<<1024, 256, 0, stream>>>(src, tgt, cursor, col, E);

    // ---- fused pipeline ----
    k_in_proj1<<<(N + 63) / 64, 512, 0, stream>>>(x, W_in, b_in, Wl1, Wr1, bl1, p1v, r1, N);
    k_agg1_proj2<<<(N + 7) / 8, 256, 0, stream>>>(p1v, r1, rowstart, col, g1, be1,
                                                  Wl2, Wr2, bl2, p2h, r2, N);
    k_agg2_out<<<(N + 15) / 16, 256, 0, stream>>>((const __half2*)p2h, r2, rowstart, col,
                                                  g2, be2, Wo1, bo1, Wo2, bo2, out, N);
}

// Round 4
// 223.597 us; speedup vs baseline: 2.2027x; 1.1355x over previous
//
#include <hip/hip_runtime.h>
#include <hip/hip_bf16.h>
#include <hip/hip_fp16.h>

#define NN 50000
#define NE 800000
#define EPS 1e-5f

typedef _Float16 f16;
typedef _Float16 f16x8 __attribute__((ext_vector_type(8)));
typedef float f32x4 __attribute__((ext_vector_type(4)));

// ---------------- CSR build ----------------

__global__ void k_zero(int* __restrict__ p, int n) {
    int i = blockIdx.x * blockDim.x + threadIdx.x;
    for (; i < n; i += gridDim.x * blockDim.x) p[i] = 0;
}

__global__ void k_hist(const int* __restrict__ tgt, int* __restrict__ deg, int E) {
    int i = blockIdx.x * blockDim.x + threadIdx.x;
    for (; i < E; i += gridDim.x * blockDim.x) atomicAdd(&deg[tgt[i]], 1);
}

__device__ __forceinline__ int waveInclScan(int v, int lane) {
#pragma unroll
    for (int o = 1; o < 64; o <<= 1) {
        int t = __shfl_up(v, o, 64);
        if (lane >= o) v += t;
    }
    return v;
}

__global__ __launch_bounds__(256) void k_scanA(const int* __restrict__ deg,
                                               int* __restrict__ locscan,
                                               int* __restrict__ bsum, int n) {
    __shared__ int wt[4];
    int tid = threadIdx.x;
    int gid = blockIdx.x * 256 + tid;
    int lane = tid & 63, w = tid >> 6;
    int v = (gid < n) ? deg[gid] : 0;
    int incl = waveInclScan(v, lane);
    if (lane == 63) wt[w] = incl;
    __syncthreads();
    int off = 0;
#pragma unroll
    for (int j = 0; j < 3; j++) if (j < w) off += wt[j];
    if (gid < n) locscan[gid] = off + incl - v;
    if (tid == 255) bsum[blockIdx.x] = off + incl;
}

__global__ __launch_bounds__(256) void k_scanB(int* __restrict__ bsum, int nb,
                                               int* __restrict__ rowend) {
    __shared__ int wt[4];
    int tid = threadIdx.x;
    int lane = tid & 63, w = tid >> 6;
    int v = (tid < nb) ? bsum[tid] : 0;
    int incl = waveInclScan(v, lane);
    if (lane == 63) wt[w] = incl;
    __syncthreads();
    int off = 0;
#pragma unroll
    for (int j = 0; j < 3; j++) if (j < w) off += wt[j];
    if (tid < nb) bsum[tid] = off + incl - v;
    if (tid == 255) rowend[0] = off + incl;
}

__global__ void k_scanC(const int* __restrict__ locscan, const int* __restrict__ bsum,
                        int* __restrict__ rowstart, int* __restrict__ cursor, int n) {
    int gid = blockIdx.x * blockDim.x + threadIdx.x;
    if (gid < n) {
        int v = locscan[gid] + bsum[blockIdx.x];
        rowstart[gid] = v;
        cursor[gid] = v;
    }
}

__global__ void k_fill(const int* __restrict__ src, const int* __restrict__ tgt,
                       int* __restrict__ cursor, int* __restrict__ col, int E) {
    int i = blockIdx.x * blockDim.x + threadIdx.x;
    for (; i < E; i += gridDim.x * blockDim.x) {
        int pos = atomicAdd(&cursor[tgt[i]], 1);
        col[pos] = src[i];
    }
}

// ---------------- MFMA fused input stage ----------------
// x -> h1 = relu(x@Win+bin) (LDS only, fp16) -> p1 = h1@Wl1 (fp16), r1 = h1@Wr1+bl1 (fp16)
// 32 nodes/block, 256 threads (4 waves). mfma_f32_16x16x32_f16.
// LDS strides padded: xs 104 halves (2-way), wB/hs 136 halves (4-way), all 16B-aligned.
__global__ __launch_bounds__(256) void k_in_proj1(const float* __restrict__ x,
                                                  const float* __restrict__ Win,
                                                  const float* __restrict__ bin,
                                                  const float* __restrict__ Wl,
                                                  const float* __restrict__ Wr,
                                                  const float* __restrict__ bl,
                                                  f16* __restrict__ p1h,
                                                  f16* __restrict__ r1h, int N) {
    __shared__ __align__(16) f16 xs[32 * 104];    //  6656 B, A-tile [node][k], k padded 96->104
    __shared__ __align__(16) f16 wB[128 * 136];   // 34816 B, B^T [c][k]: winT then w2T
    __shared__ __align__(16) f16 hs[32 * 136];    //  8704 B, h-tile [node][k]
    int tid = threadIdx.x;
    int node0 = blockIdx.x * 32;

    // stage xs: [32][96] zero-padded (k>=84 or node>=N -> 0)
    for (int i = tid; i < 32 * 96; i += 256) {
        int nd = i / 96, k = i - nd * 96;
        int g = node0 + nd;
        float v = (g < N && k < 84) ? x[(size_t)g * 84 + k] : 0.f;
        xs[nd * 104 + k] = (f16)v;
    }
    // stage Win^T: wB[c][k], k 0..95 (zero pad k>=84)
    for (int i = tid; i < 96 * 128; i += 256) {
        int k = i >> 7, c = i & 127;
        float v = (k < 84) ? Win[k * 128 + c] : 0.f;
        wB[c * 104 + k] = (f16)v;
    }
    __syncthreads();

    int lane = tid & 63;
    int wv = tid >> 6;       // wave 0..3 owns N-tiles {2wv, 2wv+1}
    int r = lane & 15;
    int q = lane >> 4;

    // GEMM1: [32 x 96] @ [96 x 128]
    f32x4 acc[2][2] = {};
    for (int ks = 0; ks < 3; ks++) {
        int k0 = ks * 32;
        f16x8 a[2], b[2];
#pragma unroll
        for (int mt = 0; mt < 2; mt++)
            a[mt] = *(const f16x8*)&xs[(mt * 16 + r) * 104 + k0 + q * 8];
#pragma unroll
        for (int nt = 0; nt < 2; nt++)
            b[nt] = *(const f16x8*)&wB[((2 * wv + nt) * 16 + r) * 104 + k0 + q * 8];
#pragma unroll
        for (int mt = 0; mt < 2; mt++)
#pragma unroll
            for (int nt = 0; nt < 2; nt++)
                acc[mt][nt] = __builtin_amdgcn_mfma_f32_16x16x32_f16(a[mt], b[nt], acc[mt][nt], 0, 0, 0);
    }
    __syncthreads();   // all reads of wB/xs done

    // epilogue 1: hs = relu(acc + bin) as fp16
#pragma unroll
    for (int nt = 0; nt < 2; nt++) {
        int c = (2 * wv + nt) * 16 + r;
        float bb = bin[c];
#pragma unroll
        for (int mt = 0; mt < 2; mt++)
#pragma unroll
            for (int v = 0; v < 4; v++) {
                int row = mt * 16 + q * 4 + v;
                float val = acc[mt][nt][v] + bb;
                hs[row * 136 + c] = (f16)(val > 0.f ? val : 0.f);
            }
    }
    // stage [Wl1 | Wr1]^T: wB[c][k], c<64 -> Wl col c, c>=64 -> Wr col c-64
    for (int i = tid; i < 128 * 128; i += 256) {
        int k = i >> 7, c = i & 127;
        float v = (c < 64) ? Wl[k * 64 + c] : Wr[k * 64 + (c - 64)];
        wB[c * 136 + k] = (f16)v;
    }
    __syncthreads();

    // GEMM2: [32 x 128] @ [128 x 128]
    f32x4 acc2[2][2] = {};
    for (int ks = 0; ks < 4; ks++) {
        int k0 = ks * 32;
        f16x8 a[2], b[2];
#pragma unroll
        for (int mt = 0; mt < 2; mt++)
            a[mt] = *(const f16x8*)&hs[(mt * 16 + r) * 136 + k0 + q * 8];
#pragma unroll
        for (int nt = 0; nt < 2; nt++)
            b[nt] = *(const f16x8*)&wB[((2 * wv + nt) * 16 + r) * 136 + k0 + q * 8];
#pragma unroll
        for (int mt = 0; mt < 2; mt++)
#pragma unroll
            for (int nt = 0; nt < 2; nt++)
                acc2[mt][nt] = __builtin_amdgcn_mfma_f32_16x16x32_f16(a[mt], b[nt], acc2[mt][nt], 0, 0, 0);
    }

    // epilogue 2: c<64 -> p1, c>=64 -> r1 (+bl)
#pragma unroll
    for (int nt = 0; nt < 2; nt++) {
        int c = (2 * wv + nt) * 16 + r;
        float bb = (c >= 64) ? bl[c - 64] : 0.f;
#pragma unroll
        for (int mt = 0; mt < 2; mt++)
#pragma unroll
            for (int v = 0; v < 4; v++) {
                int n = node0 + mt * 16 + q * 4 + v;
                if (n < N) {
                    float val = acc2[mt][nt][v];
                    if (c < 64) p1h[(size_t)n * 64 + c] = (f16)val;
                    else        r1h[(size_t)n * 64 + (c - 64)] = (f16)(val + bb);
                }
            }
    }
}

// (p1 fp16, r1 fp16, CSR) -> p2 (fp16), r2 (fp16): mean-agg + LN + relu then proj2.
// 8 nodes/block, 32 lanes (=16 half2) per node.
__global__ __launch_bounds__(256) void k_agg1_proj2(const __half2* __restrict__ p1v,
                                                    const __half2* __restrict__ r1v,
                                                    const int* __restrict__ rowstart,
                                                    const int* __restrict__ col,
                                                    const float* __restrict__ g1,
                                                    const float* __restrict__ be1,
                                                    const float* __restrict__ Wl2,
                                                    const float* __restrict__ Wr2,
                                                    const float* __restrict__ bl2,
                                                    __half* __restrict__ p2h,
                                                    __half* __restrict__ r2h, int N) {
    __shared__ float Wlds[2 * 2048];   // 16 KB: Wl2 | Wr2
    __shared__ float ylds[8][64];      // 2 KB
    int tid = threadIdx.x;
    for (int i = tid; i < 2048; i += 256) {
        Wlds[i] = Wl2[i];
        Wlds[2048 + i] = Wr2[i];
    }
    int cc = tid & 31;
    int grp = tid >> 5;
    int n = blockIdx.x * 8 + grp;
    if (n < N) {
        int s0 = rowstart[n], s1 = rowstart[n + 1];
        float2 a0 = make_float2(0.f, 0.f), a1 = a0, a2 = a0, a3 = a0;
        int i = s0;
        for (; i + 3 < s1; i += 4) {
            float2 v0 = __half22float2(p1v[(size_t)col[i]     * 32 + cc]);
            float2 v1 = __half22float2(p1v[(size_t)col[i + 1] * 32 + cc]);
            float2 v2 = __half22float2(p1v[(size_t)col[i + 2] * 32 + cc]);
            float2 v3 = __half22float2(p1v[(size_t)col[i + 3] * 32 + cc]);
            a0.x += v0.x; a0.y += v0.y;
            a1.x += v1.x; a1.y += v1.y;
            a2.x += v2.x; a2.y += v2.y;
            a3.x += v3.x; a3.y += v3.y;
        }
        for (; i < s1; i++) {
            float2 v0 = __half22float2(p1v[(size_t)col[i] * 32 + cc]);
            a0.x += v0.x; a0.y += v0.y;
        }
        float sx = a0.x + a1.x + a2.x + a3.x;
        float sy = a0.y + a1.y + a2.y + a3.y;
        int cnt = s1 - s0;
        float inv = 1.f / (float)(cnt > 1 ? cnt : 1);
        float2 rr = __half22float2(r1v[(size_t)n * 32 + cc]);
        float vx = sx * inv + rr.x;
        float vy = sy * inv + rr.y;
        float s = vx + vy;
#pragma unroll
        for (int o = 1; o < 32; o <<= 1) s += __shfl_xor(s, o, 32);
        float m = s * (1.f / 64.f);
        float dx = vx - m, dy = vy - m;
        float qv = dx * dx + dy * dy;
#pragma unroll
        for (int o = 1; o < 32; o <<= 1) qv += __shfl_xor(qv, o, 32);
        float rs = rsqrtf(qv * (1.f / 64.f) + EPS);
        float y0 = dx * rs * g1[2 * cc] + be1[2 * cc];
        float y1 = dy * rs * g1[2 * cc + 1] + be1[2 * cc + 1];
        ylds[grp][2 * cc]     = y0 > 0.f ? y0 : 0.f;
        ylds[grp][2 * cc + 1] = y1 > 0.f ? y1 : 0.f;
    }
    __syncthreads();
    if (n < N) {
        const float* yr = ylds[grp];
        float ap = 0.f, ar = 0.f;
#pragma unroll 4
        for (int k = 0; k < 64; k++) {
            float y = yr[k];
            ap += y * Wlds[k * 32 + cc];
            ar += y * Wlds[2048 + k * 32 + cc];
        }
        p2h[(size_t)n * 32 + cc] = __float2half_rn(ap);
        r2h[(size_t)n * 32 + cc] = __float2half_rn(ar + bl2[cc]);
    }
}

// (p2 fp16, r2 fp16, CSR) -> out : mean-agg + LN + relu + 2-layer MLP.
// 16 nodes/block, 16 lanes per node (2 channels/lane).
__global__ __launch_bounds__(256) void k_agg2_out(const __half2* __restrict__ p2v,
                                                  const __half2* __restrict__ r2v,
                                                  const int* __restrict__ rowstart,
                                                  const int* __restrict__ col,
                                                  const float* __restrict__ g2,
                                                  const float* __restrict__ be2,
                                                  const float* __restrict__ Wo1,
                                                  const float* __restrict__ bo1,
                                                  const float* __restrict__ Wo2,
                                                  const float* __restrict__ bo2,
                                                  float* __restrict__ out, int N) {
    __shared__ float W1[32 * 16];
    __shared__ float ylds[16][32];
    __shared__ float b1s[16], w2s[16], b2s;
    int tid = threadIdx.x;
    for (int i = tid; i < 32 * 16; i += 256) W1[i] = Wo1[i];
    if (tid < 16) { b1s[tid] = bo1[tid]; w2s[tid] = Wo2[tid]; }
    if (tid == 0) b2s = bo2[0];
    int l = tid & 15;
    int grp = tid >> 4;
    int n = blockIdx.x * 16 + grp;
    if (n < N) {
        int s0 = rowstart[n], s1 = rowstart[n + 1];
        float2 a0 = make_float2(0.f, 0.f), a1 = a0, a2 = a0, a3 = a0;
        int i = s0;
        for (; i + 3 < s1; i += 4) {
            float2 v0 = __half22float2(p2v[(size_t)col[i]     * 16 + l]);
            float2 v1 = __half22float2(p2v[(size_t)col[i + 1] * 16 + l]);
            float2 v2 = __half22float2(p2v[(size_t)col[i + 2] * 16 + l]);
            float2 v3 = __half22float2(p2v[(size_t)col[i + 3] * 16 + l]);
            a0.x += v0.x; a0.y += v0.y;
            a1.x += v1.x; a1.y += v1.y;
            a2.x += v2.x; a2.y += v2.y;
            a3.x += v3.x; a3.y += v3.y;
        }
        for (; i < s1; i++) {
            float2 v0 = __half22float2(p2v[(size_t)col[i] * 16 + l]);
            a0.x += v0.x; a0.y += v0.y;
        }
        float sx = a0.x + a1.x + a2.x + a3.x;
        float sy = a0.y + a1.y + a2.y + a3.y;
        int cnt = s1 - s0;
        float inv = 1.f / (float)(cnt > 1 ? cnt : 1);
        float2 rr = __half22float2(r2v[(size_t)n * 16 + l]);
        float vx = sx * inv + rr.x;
        float vy = sy * inv + rr.y;
        float s = vx + vy;
#pragma unroll
        for (int o = 1; o < 16; o <<= 1) s += __shfl_xor(s, o, 16);
        float m = s * (1.f / 32.f);
        float dx = vx - m, dy = vy - m;
        float qv = dx * dx + dy * dy;
#pragma unroll
        for (int o = 1; o < 16; o <<= 1) qv += __shfl_xor(qv, o, 16);
        float rs = rsqrtf(qv * (1.f / 32.f) + EPS);
        float y0 = dx * rs * g2[2 * l] + be2[2 * l];
        float y1 = dy * rs * g2[2 * l + 1] + be2[2 * l + 1];
        ylds[grp][2 * l]     = y0 > 0.f ? y0 : 0.f;
        ylds[grp][2 * l + 1] = y1 > 0.f ? y1 : 0.f;
    }
    __syncthreads();
    if (n < N) {
        const float* yr = ylds[grp];
        float a = b1s[l];
#pragma unroll
        for (int k = 0; k < 32; k++) a += yr[k] * W1[k * 16 + l];
        a = a > 0.f ? a : 0.f;
        float contrib = a * w2s[l];
#pragma unroll
        for (int o = 1; o < 16; o <<= 1) contrib += __shfl_xor(contrib, o, 16);
        if (l == 0) out[n] = contrib + b2s;
    }
}

extern "C" void kernel_launch(void* const* d_in, const int* in_sizes, int n_in,
                              void* d_out, int out_size, void* d_ws, size_t ws_size,
                              hipStream_t stream) {
    const float* x    = (const float*)d_in[0];
    const int*   ei   = (const int*)d_in[1];
    const float* W_in = (const float*)d_in[2];
    const float* b_in = (const float*)d_in[3];
    const float* Wl1  = (const float*)d_in[4];
    const float* bl1  = (const float*)d_in[5];
    const float* Wr1  = (const float*)d_in[6];
    const float* g1   = (const float*)d_in[7];
    const float* be1  = (const float*)d_in[8];
    const float* Wl2  = (const float*)d_in[9];
    const float* bl2  = (const float*)d_in[10];
    const float* Wr2  = (const float*)d_in[11];
    const float* g2   = (const float*)d_in[12];
    const float* be2  = (const float*)d_in[13];
    const float* Wo1  = (const float*)d_in[14];
    const float* bo1  = (const float*)d_in[15];
    const float* Wo2  = (const float*)d_in[16];
    const float* bo2  = (const float*)d_in[17];
    float* out = (float*)d_out;

    const int N = NN, E = NE;
    const int* src = ei;
    const int* tgt = ei + E;
    const int SB = (N + 255) / 256;   // 196

    // workspace layout
    char* w = (char*)d_ws;
    int* deg      = (int*)w;  w += (size_t)N * 4;
    int* locscan  = (int*)w;  w += (size_t)N * 4;
    int* bsum     = (int*)w;  w += 256 * 4;
    int* rowstart = (int*)w;  w += (size_t)(N + 1) * 4;
    int* cursor   = (int*)w;  w += (size_t)N * 4;
    int* col      = (int*)w;  w += (size_t)E * 4;
    w = (char*)(((uintptr_t)w + 15) & ~(uintptr_t)15);
    f16* p1h = (f16*)w;  w += (size_t)N * 64 * 2;   // N x 64 fp16
    f16* r1h = (f16*)w;  w += (size_t)N * 64 * 2;   // N x 64 fp16
    f16* p2h = (f16*)w;  w += (size_t)N * 32 * 2;   // N x 32 fp16
    f16* r2h = (f16*)w;  w += (size_t)N * 32 * 2;   // N x 32 fp16

    // ---- CSR build ----
    k_zero<<<128, 256, 0, stream>>>(deg, N);
    k_hist<<<1024, 256, 0, stream>>>(tgt, deg, E);
    k_scanA<<<SB, 256, 0, stream>>>(deg, locscan, bsum, N);
    k_scanB<<<1, 256, 0, stream>>>(bsum, SB, rowstart + N);
    k_scanC<<<SB, 256, 0, stream>>>(locscan, bsum, rowstart, cursor, N);
    k_fill<<<1024, 256, 0, stream>>>(src, tgt, cursor, col, E);

    // ---- fused pipeline ----
    k_in_proj1<<<(N + 31) / 32, 256, 0, stream>>>(x, W_in, b_in, Wl1, Wr1, bl1, p1h, r1h, N);
    k_agg1_proj2<<<(N + 7) / 8, 256, 0, stream>>>((const __half2*)p1h, (const __half2*)r1h,
                                                  rowstart, col, g1, be1,
                                                  Wl2, Wr2, bl2, (__half*)p2h, (__half*)r2h, N);
    k_agg2_out<<<(N + 15) / 16, 256, 0, stream>>>((const __half2*)p2h, (const __half2*)r2h,
                                                  rowstart, col, g2, be2,
                                                  Wo1, bo1, Wo2, bo2, out, N);
}

// Round 5
// 183.338 us; speedup vs baseline: 2.6863x; 1.2196x over previous
//
#include <hip/hip_runtime.h>
#include <hip/hip_bf16.h>
#include <hip/hip_fp16.h>

#define NN 50000
#define NE 800000
#define EPS 1e-5f

typedef _Float16 f16;
typedef _Float16 f16x8 __attribute__((ext_vector_type(8)));
typedef float f32x4 __attribute__((ext_vector_type(4)));

// ---------------- CSR build ----------------

__global__ void k_zero(int* __restrict__ p, int n) {
    int i = blockIdx.x * blockDim.x + threadIdx.x;
    for (; i < n; i += gridDim.x * blockDim.x) p[i] = 0;
}

// 4-wide batched histogram: 4 independent atomics in flight per thread
__global__ void k_hist(const int* __restrict__ tgt, int* __restrict__ deg, int E4) {
    int i = blockIdx.x * blockDim.x + threadIdx.x;
    for (; i < E4; i += gridDim.x * blockDim.x) {
        int4 t = ((const int4*)tgt)[i];
        atomicAdd(&deg[t.x], 1);
        atomicAdd(&deg[t.y], 1);
        atomicAdd(&deg[t.z], 1);
        atomicAdd(&deg[t.w], 1);
    }
}

__device__ __forceinline__ int waveInclScan(int v, int lane) {
#pragma unroll
    for (int o = 1; o < 64; o <<= 1) {
        int t = __shfl_up(v, o, 64);
        if (lane >= o) v += t;
    }
    return v;
}

__global__ __launch_bounds__(256) void k_scanA(const int* __restrict__ deg,
                                               int* __restrict__ locscan,
                                               int* __restrict__ bsum, int n) {
    __shared__ int wt[4];
    int tid = threadIdx.x;
    int gid = blockIdx.x * 256 + tid;
    int lane = tid & 63, w = tid >> 6;
    int v = (gid < n) ? deg[gid] : 0;
    int incl = waveInclScan(v, lane);
    if (lane == 63) wt[w] = incl;
    __syncthreads();
    int off = 0;
#pragma unroll
    for (int j = 0; j < 3; j++) if (j < w) off += wt[j];
    if (gid < n) locscan[gid] = off + incl - v;
    if (tid == 255) bsum[blockIdx.x] = off + incl;
}

__global__ __launch_bounds__(256) void k_scanB(int* __restrict__ bsum, int nb,
                                               int* __restrict__ rowend) {
    __shared__ int wt[4];
    int tid = threadIdx.x;
    int lane = tid & 63, w = tid >> 6;
    int v = (tid < nb) ? bsum[tid] : 0;
    int incl = waveInclScan(v, lane);
    if (lane == 63) wt[w] = incl;
    __syncthreads();
    int off = 0;
#pragma unroll
    for (int j = 0; j < 3; j++) if (j < w) off += wt[j];
    if (tid < nb) bsum[tid] = off + incl - v;
    if (tid == 255) rowend[0] = off + incl;
}

__global__ void k_scanC(const int* __restrict__ locscan, const int* __restrict__ bsum,
                        int* __restrict__ rowstart, int* __restrict__ cursor, int n) {
    int gid = blockIdx.x * blockDim.x + threadIdx.x;
    if (gid < n) {
        int v = locscan[gid] + bsum[blockIdx.x];
        rowstart[gid] = v;
        cursor[gid] = v;
    }
}

// 4-wide batched fill: int4 loads, 4 atomics, 4 scatters per thread
__global__ void k_fill(const int* __restrict__ src, const int* __restrict__ tgt,
                       int* __restrict__ cursor, int* __restrict__ col, int E4) {
    int i = blockIdx.x * blockDim.x + threadIdx.x;
    for (; i < E4; i += gridDim.x * blockDim.x) {
        int4 t = ((const int4*)tgt)[i];
        int4 s = ((const int4*)src)[i];
        int p0 = atomicAdd(&cursor[t.x], 1);
        int p1 = atomicAdd(&cursor[t.y], 1);
        int p2 = atomicAdd(&cursor[t.z], 1);
        int p3 = atomicAdd(&cursor[t.w], 1);
        col[p0] = s.x;
        col[p1] = s.y;
        col[p2] = s.z;
        col[p3] = s.w;
    }
}

// ---------------- weight prep (once per launch, tiny) ----------------
// WinT: [128][104] fp16, [c][k] = Win[k*128+c] (k<84, else 0)
// W2T : [128][136] fp16, [c][k] = c<64 ? Wl1[k*64+c] : Wr1[k*64+c-64] (k<128, else 0)
__global__ __launch_bounds__(256) void k_prep(const float* __restrict__ Win,
                                              const float* __restrict__ Wl,
                                              const float* __restrict__ Wr,
                                              f16* __restrict__ WinT,
                                              f16* __restrict__ W2T) {
    int i0 = blockIdx.x * 256 + threadIdx.x;
    for (int i = i0; i < 128 * 104; i += gridDim.x * 256) {
        int c = i / 104, k = i - c * 104;
        float v = (k < 84) ? Win[k * 128 + c] : 0.f;
        WinT[c * 104 + k] = (f16)v;
    }
    for (int i = i0; i < 128 * 136; i += gridDim.x * 256) {
        int c = i / 136, k = i - c * 136;
        float v = 0.f;
        if (k < 128) v = (c < 64) ? Wl[k * 64 + c] : Wr[k * 64 + (c - 64)];
        W2T[c * 136 + k] = (f16)v;
    }
}

// ---------------- MFMA fused input stage ----------------
// x -> h1 = relu(x@Win+bin) (LDS fp16) -> p1 = h1@Wl1, r1 = h1@Wr1+bl1 (fp16 out)
// 32 nodes/block, 256 threads (4 waves). B-operands in registers from prepped arrays.
__global__ __launch_bounds__(256) void k_in_proj1(const float* __restrict__ x,
                                                  const f16* __restrict__ WinT,
                                                  const float* __restrict__ bin,
                                                  const f16* __restrict__ W2T,
                                                  const float* __restrict__ bl,
                                                  f16* __restrict__ p1h,
                                                  f16* __restrict__ r1h, int N) {
    __shared__ __align__(16) f16 xs[32 * 104];   // 6656 B
    __shared__ __align__(16) f16 hs[32 * 136];   // 8704 B
    int tid = threadIdx.x;
    int node0 = blockIdx.x * 32;
    int lane = tid & 63;
    int wv = tid >> 6;       // wave 0..3 owns c-tiles {2wv, 2wv+1}
    int r = lane & 15;
    int q = lane >> 4;

    // B-fragments for GEMM1 straight from global (L2-hot)
    f16x8 b1[2][3];
#pragma unroll
    for (int nt = 0; nt < 2; nt++) {
        int c = (2 * wv + nt) * 16 + r;
#pragma unroll
        for (int ks = 0; ks < 3; ks++)
            b1[nt][ks] = *(const f16x8*)&WinT[c * 104 + ks * 32 + q * 8];
    }

    // stage xs: [32][96] zero-padded (k>=84 or node>=N -> 0)
    for (int i = tid; i < 32 * 96; i += 256) {
        int nd = i / 96, k = i - nd * 96;
        int g = node0 + nd;
        float v = (g < N && k < 84) ? x[(size_t)g * 84 + k] : 0.f;
        xs[nd * 104 + k] = (f16)v;
    }
    __syncthreads();

    // GEMM1: [32 x 96] @ [96 x 128]
    f32x4 acc[2][2] = {};
#pragma unroll
    for (int ks = 0; ks < 3; ks++) {
        int k0 = ks * 32;
        f16x8 a[2];
#pragma unroll
        for (int mt = 0; mt < 2; mt++)
            a[mt] = *(const f16x8*)&xs[(mt * 16 + r) * 104 + k0 + q * 8];
#pragma unroll
        for (int mt = 0; mt < 2; mt++)
#pragma unroll
            for (int nt = 0; nt < 2; nt++)
                acc[mt][nt] = __builtin_amdgcn_mfma_f32_16x16x32_f16(a[mt], b1[nt][ks], acc[mt][nt], 0, 0, 0);
    }

    // B-fragments for GEMM2
    f16x8 b2[2][4];
#pragma unroll
    for (int nt = 0; nt < 2; nt++) {
        int c = (2 * wv + nt) * 16 + r;
#pragma unroll
        for (int ks = 0; ks < 4; ks++)
            b2[nt][ks] = *(const f16x8*)&W2T[c * 136 + ks * 32 + q * 8];
    }

    // epilogue 1: hs = relu(acc + bin) as fp16
#pragma unroll
    for (int nt = 0; nt < 2; nt++) {
        int c = (2 * wv + nt) * 16 + r;
        float bb = bin[c];
#pragma unroll
        for (int mt = 0; mt < 2; mt++)
#pragma unroll
            for (int v = 0; v < 4; v++) {
                int row = mt * 16 + q * 4 + v;
                float val = acc[mt][nt][v] + bb;
                hs[row * 136 + c] = (f16)(val > 0.f ? val : 0.f);
            }
    }
    __syncthreads();

    // GEMM2: [32 x 128] @ [128 x 128]
    f32x4 acc2[2][2] = {};
#pragma unroll
    for (int ks = 0; ks < 4; ks++) {
        int k0 = ks * 32;
        f16x8 a[2];
#pragma unroll
        for (int mt = 0; mt < 2; mt++)
            a[mt] = *(const f16x8*)&hs[(mt * 16 + r) * 136 + k0 + q * 8];
#pragma unroll
        for (int mt = 0; mt < 2; mt++)
#pragma unroll
            for (int nt = 0; nt < 2; nt++)
                acc2[mt][nt] = __builtin_amdgcn_mfma_f32_16x16x32_f16(a[mt], b2[nt][ks], acc2[mt][nt], 0, 0, 0);
    }

    // epilogue 2: c<64 -> p1, c>=64 -> r1 (+bl)
#pragma unroll
    for (int nt = 0; nt < 2; nt++) {
        int c = (2 * wv + nt) * 16 + r;
        float bb = (c >= 64) ? bl[c - 64] : 0.f;
#pragma unroll
        for (int mt = 0; mt < 2; mt++)
#pragma unroll
            for (int v = 0; v < 4; v++) {
                int n = node0 + mt * 16 + q * 4 + v;
                if (n < N) {
                    float val = acc2[mt][nt][v];
                    if (c < 64) p1h[(size_t)n * 64 + c] = (f16)val;
                    else        r1h[(size_t)n * 64 + (c - 64)] = (f16)(val + bb);
                }
            }
    }
}

// (p1 fp16, r1 fp16, CSR) -> p2 (fp16), r2 (fp16): mean-agg + LN + relu then proj2.
// 8 nodes/block, 32 lanes (=16 half2) per node.
__global__ __launch_bounds__(256) void k_agg1_proj2(const __half2* __restrict__ p1v,
                                                    const __half2* __restrict__ r1v,
                                                    const int* __restrict__ rowstart,
                                                    const int* __restrict__ col,
                                                    const float* __restrict__ g1,
                                                    const float* __restrict__ be1,
                                                    const float* __restrict__ Wl2,
                                                    const float* __restrict__ Wr2,
                                                    const float* __restrict__ bl2,
                                                    __half* __restrict__ p2h,
                                                    __half* __restrict__ r2h, int N) {
    __shared__ float Wlds[2 * 2048];   // 16 KB: Wl2 | Wr2
    __shared__ float ylds[8][64];      // 2 KB
    int tid = threadIdx.x;
    for (int i = tid; i < 2048; i += 256) {
        Wlds[i] = Wl2[i];
        Wlds[2048 + i] = Wr2[i];
    }
    int cc = tid & 31;
    int grp = tid >> 5;
    int n = blockIdx.x * 8 + grp;
    if (n < N) {
        int s0 = rowstart[n], s1 = rowstart[n + 1];
        float2 a0 = make_float2(0.f, 0.f), a1 = a0, a2 = a0, a3 = a0;
        int i = s0;
        for (; i + 3 < s1; i += 4) {
            float2 v0 = __half22float2(p1v[(size_t)col[i]     * 32 + cc]);
            float2 v1 = __half22float2(p1v[(size_t)col[i + 1] * 32 + cc]);
            float2 v2 = __half22float2(p1v[(size_t)col[i + 2] * 32 + cc]);
            float2 v3 = __half22float2(p1v[(size_t)col[i + 3] * 32 + cc]);
            a0.x += v0.x; a0.y += v0.y;
            a1.x += v1.x; a1.y += v1.y;
            a2.x += v2.x; a2.y += v2.y;
            a3.x += v3.x; a3.y += v3.y;
        }
        for (; i < s1; i++) {
            float2 v0 = __half22float2(p1v[(size_t)col[i] * 32 + cc]);
            a0.x += v0.x; a0.y += v0.y;
        }
        float sx = a0.x + a1.x + a2.x + a3.x;
        float sy = a0.y + a1.y + a2.y + a3.y;
        int cnt = s1 - s0;
        float inv = 1.f / (float)(cnt > 1 ? cnt : 1);
        float2 rr = __half22float2(r1v[(size_t)n * 32 + cc]);
        float vx = sx * inv + rr.x;
        float vy = sy * inv + rr.y;
        float s = vx + vy;
#pragma unroll
        for (int o = 1; o < 32; o <<= 1) s += __shfl_xor(s, o, 32);
        float m = s * (1.f / 64.f);
        float dx = vx - m, dy = vy - m;
        float qv = dx * dx + dy * dy;
#pragma unroll
        for (int o = 1; o < 32; o <<= 1) qv += __shfl_xor(qv, o, 32);
        float rs = rsqrtf(qv * (1.f / 64.f) + EPS);
        float y0 = dx * rs * g1[2 * cc] + be1[2 * cc];
        float y1 = dy * rs * g1[2 * cc + 1] + be1[2 * cc + 1];
        ylds[grp][2 * cc]     = y0 > 0.f ? y0 : 0.f;
        ylds[grp][2 * cc + 1] = y1 > 0.f ? y1 : 0.f;
    }
    __syncthreads();
    if (n < N) {
        const float* yr = ylds[grp];
        float ap = 0.f, ar = 0.f;
#pragma unroll 4
        for (int k = 0; k < 64; k++) {
            float y = yr[k];
            ap += y * Wlds[k * 32 + cc];
            ar += y * Wlds[2048 + k * 32 + cc];
        }
        p2h[(size_t)n * 32 + cc] = __float2half_rn(ap);
        r2h[(size_t)n * 32 + cc] = __float2half_rn(ar + bl2[cc]);
    }
}

// (p2 fp16, r2 fp16, CSR) -> out : mean-agg + LN + relu + 2-layer MLP.
// 16 nodes/block, 16 lanes per node (2 channels/lane).
__global__ __launch_bounds__(256) void k_agg2_out(const __half2* __restrict__ p2v,
                                                  const __half2* __restrict__ r2v,
                                                  const int* __restrict__ rowstart,
                                                  const int* __restrict__ col,
                                                  const float* __restrict__ g2,
                                                  const float* __restrict__ be2,
                                                  const float* __restrict__ Wo1,
                                                  const float* __restrict__ bo1,
                                                  const float* __restrict__ Wo2,
                                                  const float* __restrict__ bo2,
                                                  float* __restrict__ out, int N) {
    __shared__ float W1[32 * 16];
    __shared__ float ylds[16][32];
    __shared__ float b1s[16], w2s[16], b2s;
    int tid = threadIdx.x;
    for (int i = tid; i < 32 * 16; i += 256) W1[i] = Wo1[i];
    if (tid < 16) { b1s[tid] = bo1[tid]; w2s[tid] = Wo2[tid]; }
    if (tid == 0) b2s = bo2[0];
    int l = tid & 15;
    int grp = tid >> 4;
    int n = blockIdx.x * 16 + grp;
    if (n < N) {
        int s0 = rowstart[n], s1 = rowstart[n + 1];
        float2 a0 = make_float2(0.f, 0.f), a1 = a0, a2 = a0, a3 = a0;
        int i = s0;
        for (; i + 3 < s1; i += 4) {
            float2 v0 = __half22float2(p2v[(size_t)col[i]     * 16 + l]);
            float2 v1 = __half22float2(p2v[(size_t)col[i + 1] * 16 + l]);
            float2 v2 = __half22float2(p2v[(size_t)col[i + 2] * 16 + l]);
            float2 v3 = __half22float2(p2v[(size_t)col[i + 3] * 16 + l]);
            a0.x += v0.x; a0.y += v0.y;
            a1.x += v1.x; a1.y += v1.y;
            a2.x += v2.x; a2.y += v2.y;
            a3.x += v3.x; a3.y += v3.y;
        }
        for (; i < s1; i++) {
            float2 v0 = __half22float2(p2v[(size_t)col[i] * 16 + l]);
            a0.x += v0.x; a0.y += v0.y;
        }
        float sx = a0.x + a1.x + a2.x + a3.x;
        float sy = a0.y + a1.y + a2.y + a3.y;
        int cnt = s1 - s0;
        float inv = 1.f / (float)(cnt > 1 ? cnt : 1);
        float2 rr = __half22float2(r2v[(size_t)n * 16 + l]);
        float vx = sx * inv + rr.x;
        float vy = sy * inv + rr.y;
        float s = vx + vy;
#pragma unroll
        for (int o = 1; o < 16; o <<= 1) s += __shfl_xor(s, o, 16);
        float m = s * (1.f / 32.f);
        float dx = vx - m, dy = vy - m;
        float qv = dx * dx + dy * dy;
#pragma unroll
        for (int o = 1; o < 16; o <<= 1) qv += __shfl_xor(qv, o, 16);
        float rs = rsqrtf(qv * (1.f / 32.f) + EPS);
        float y0 = dx * rs * g2[2 * l] + be2[2 * l];
        float y1 = dy * rs * g2[2 * l + 1] + be2[2 * l + 1];
        ylds[grp][2 * l]     = y0 > 0.f ? y0 : 0.f;
        ylds[grp][2 * l + 1] = y1 > 0.f ? y1 : 0.f;
    }
    __syncthreads();
    if (n < N) {
        const float* yr = ylds[grp];
        float a = b1s[l];
#pragma unroll
        for (int k = 0; k < 32; k++) a += yr[k] * W1[k * 16 + l];
        a = a > 0.f ? a : 0.f;
        float contrib = a * w2s[l];
#pragma unroll
        for (int o = 1; o < 16; o <<= 1) contrib += __shfl_xor(contrib, o, 16);
        if (l == 0) out[n] = contrib + b2s;
    }
}

extern "C" void kernel_launch(void* const* d_in, const int* in_sizes, int n_in,
                              void* d_out, int out_size, void* d_ws, size_t ws_size,
                              hipStream_t stream) {
    const float* x    = (const float*)d_in[0];
    const int*   ei   = (const int*)d_in[1];
    const float* W_in = (const float*)d_in[2];
    const float* b_in = (const float*)d_in[3];
    const float* Wl1  = (const float*)d_in[4];
    const float* bl1  = (const float*)d_in[5];
    const float* Wr1  = (const float*)d_in[6];
    const float* g1   = (const float*)d_in[7];
    const float* be1  = (const float*)d_in[8];
    const float* Wl2  = (const float*)d_in[9];
    const float* bl2  = (const float*)d_in[10];
    const float* Wr2  = (const float*)d_in[11];
    const float* g2   = (const float*)d_in[12];
    const float* be2  = (const float*)d_in[13];
    const float* Wo1  = (const float*)d_in[14];
    const float* bo1  = (const float*)d_in[15];
    const float* Wo2  = (const float*)d_in[16];
    const float* bo2  = (const float*)d_in[17];
    float* out = (float*)d_out;

    const int N = NN, E = NE;
    const int* src = ei;
    const int* tgt = ei + E;
    const int SB = (N + 255) / 256;   // 196

    // workspace layout
    char* w = (char*)d_ws;
    int* deg      = (int*)w;  w += (size_t)N * 4;
    int* locscan  = (int*)w;  w += (size_t)N * 4;
    int* bsum     = (int*)w;  w += 256 * 4;
    int* rowstart = (int*)w;  w += (size_t)(N + 1) * 4;
    int* cursor   = (int*)w;  w += (size_t)N * 4;
    int* col      = (int*)w;  w += (size_t)E * 4;
    w = (char*)(((uintptr_t)w + 15) & ~(uintptr_t)15);
    f16* p1h  = (f16*)w;  w += (size_t)N * 64 * 2;
    f16* r1h  = (f16*)w;  w += (size_t)N * 64 * 2;
    f16* p2h  = (f16*)w;  w += (size_t)N * 32 * 2;
    f16* r2h  = (f16*)w;  w += (size_t)N * 32 * 2;
    f16* WinT = (f16*)w;  w += (size_t)128 * 104 * 2;
    f16* W2T  = (f16*)w;  w += (size_t)128 * 136 * 2;

    // ---- weight prep + CSR build ----
    k_prep<<<68, 256, 0, stream>>>(W_in, Wl1, Wr1, WinT, W2T);
    k_zero<<<128, 256, 0, stream>>>(deg, N);
    k_hist<<<512, 256, 0, stream>>>(tgt, deg, E / 4);
    k_scanA<<<SB, 256, 0, stream>>>(deg, locscan, bsum, N);
    k_scanB<<<1, 256, 0, stream>>>(bsum, SB, rowstart + N);
    k_scanC<<<SB, 256, 0, stream>>>(locscan, bsum, rowstart, cursor, N);
    k_fill<<<800, 256, 0, stream>>>(src, tgt, cursor, col, E / 4);

    // ---- fused pipeline ----
    k_in_proj1<<<(N + 31) / 32, 256, 0, stream>>>(x, WinT, b_in, W2T, bl1, p1h, r1h, N);
    k_agg1_proj2<<<(N + 7) / 8, 256, 0, stream>>>((const __half2*)p1h, (const __half2*)r1h,
                                                  rowstart, col, g1, be1,
                                                  Wl2, Wr2, bl2, (__half*)p2h, (__half*)r2h, N);
    k_agg2_out<<<(N + 15) / 16, 256, 0, stream>>>((const __half2*)p2h, (const __half2*)r2h,
                                                  rowstart, col, g2, be2,
                                                  Wo1, bo1, Wo2, bo2, out, N);
}